// Round 20
// baseline (297.919 us; speedup 1.0000x reference)
//
#include <hip/hip_runtime.h>
#include <cstdint>
#include <cstddef>

#define B_    16
#define S_    1024
#define DIM_  1024
#define H_    16
#define HD_   64
#define TDIM  3072   // 3*DIM

typedef unsigned short ushort_t;
typedef unsigned int   uint_t;
typedef __attribute__((ext_vector_type(8)))  short s8v;    // 8 bf16 = 4 VGPRs
typedef __attribute__((ext_vector_type(4)))  float f32x4;
typedef __attribute__((ext_vector_type(16))) float f32x16;

__device__ __forceinline__ float b2f(ushort_t u) {
    union { uint_t i; float f; } t; t.i = (uint_t)u << 16; return t.f;
}
__device__ __forceinline__ ushort_t f2b(float f) {
    union { float f; uint_t i; } t; t.f = f;
    uint_t r = t.i + 0x7FFFu + ((t.i >> 16) & 1u);   // RNE
    return (ushort_t)(r >> 16);
}
__device__ __forceinline__ uint_t cvt_pk_bf16(float a, float b) {
    uint_t r;
    asm("v_cvt_pk_bf16_f32 %0, %1, %2" : "=v"(r) : "v"(a), "v"(b));
    return r;
}

// 16x16x32: D[m][n] += sum_k A[m,k]*B[k,n]
// D-frag (HW-verified m89/m91): col=lane&15, row=(lane>>4)*4+reg.
__device__ __forceinline__ f32x4 mfma_bf16(s8v a, s8v b, f32x4 c) {
    asm volatile("v_mfma_f32_16x16x32_bf16 %0, %1, %2, %0" : "+v"(c) : "v"(a), "v"(b));
    return c;
}
// 32x32x16: D-frag (HW-verified m74/m101): col=lane&31, row=(reg&3)+8*(reg>>2)+4*(lane>>5)
__device__ __forceinline__ f32x16 mfma32_bf16(s8v a, s8v b, f32x16 c) {
    asm volatile("v_mfma_f32_32x32x16_bf16 %0, %1, %2, %0" : "+v"(c) : "v"(a), "v"(b));
    return c;
}

// async global->LDS, 16B per lane; LDS dest = wave-uniform base + lane*16.
__device__ __forceinline__ void gload16(const void* g, void* l) {
    __builtin_amdgcn_global_load_lds(
        (const __attribute__((address_space(1))) uint_t*)g,
        (__attribute__((address_space(3))) uint_t*)l, 16, 0, 0);
}

// raw barrier (no compiler vmcnt drain) + explicit vm waits
__device__ __forceinline__ void bar() {
    asm volatile("" ::: "memory");
    __builtin_amdgcn_s_barrier();
    asm volatile("" ::: "memory");
}
__device__ __forceinline__ void wait_vm0() {
    asm volatile("s_waitcnt vmcnt(0)" ::: "memory");
}
__device__ __forceinline__ void wait_vm4() {
    asm volatile("s_waitcnt vmcnt(4)" ::: "memory");
}

// ---------------------------------------------------------------------------
// fp32 -> bf16, 8 elements/thread
// ---------------------------------------------------------------------------
__global__ __launch_bounds__(256) void f32_to_bf16_vec(const float* __restrict__ src,
                                                       short* __restrict__ dst, int n8) {
    int i = blockIdx.x * 256 + threadIdx.x;
    if (i < n8) {
        float4 a = *(const float4*)(src + (size_t)i * 8);
        float4 b = *(const float4*)(src + (size_t)i * 8 + 4);
        s8v t;
        t[0] = (short)f2b(a.x); t[1] = (short)f2b(a.y);
        t[2] = (short)f2b(a.z); t[3] = (short)f2b(a.w);
        t[4] = (short)f2b(b.x); t[5] = (short)f2b(b.y);
        t[6] = (short)f2b(b.z); t[7] = (short)f2b(b.w);
        *(s8v*)(dst + (size_t)i * 8) = t;
    }
}

// ---------------------------------------------------------------------------
// RoPE cos/sin tables [S][HD] fp32
// ---------------------------------------------------------------------------
__global__ __launch_bounds__(256) void rope_tables(float* __restrict__ cos_t,
                                                   float* __restrict__ sin_t) {
    int idx = blockIdx.x * 256 + threadIdx.x;     // 0 .. 65535
    int s = idx >> 6;
    int d = idx & 63;
    int pos = (d < 32) ? (s >> 5) : (s & 31);
    int i   = (d & 31) >> 1;
    float freq  = expf(-(float)i * 0.5756462732485115f);   // ln(10000)/16
    float angle = (float)pos * 0.5f * freq;
    cos_t[idx] = cosf(angle);
    sin_t[idx] = sinf(angle);
}

// ---------------------------------------------------------------------------
// W[K][N] fp32 -> WT[N][K] bf16  (32x32 LDS tile transpose)
// ---------------------------------------------------------------------------
__global__ __launch_bounds__(256) void transpose_to_bf16(const float* __restrict__ Wsrc,
                                                         short* __restrict__ WT,
                                                         int K, int N) {
    __shared__ float t[32][33];
    int tx = threadIdx.x & 31, ty = threadIdx.x >> 5;   // ty 0..7
    int n0 = blockIdx.x * 32, k0 = blockIdx.y * 32;
#pragma unroll
    for (int i = 0; i < 4; ++i)
        t[ty + 8 * i][tx] = Wsrc[(size_t)(k0 + ty + 8 * i) * N + n0 + tx];
    __syncthreads();
#pragma unroll
    for (int i = 0; i < 4; ++i)
        WT[(size_t)(n0 + ty + 8 * i) * K + k0 + tx] = (short)f2b(t[tx][ty + 8 * i]);
}

// ---------------------------------------------------------------------------
// 256x256 bf16 MFMA GEMM, BK=32, TRIPLE-buffered A and B (96 KiB LDS):
//   two-tile-deep staging: tile t stages tile t+2 (4 gloads); vmcnt(4) at
//   tile top confirms t+1's stages (issued a FULL TILE earlier, ~1500 cyc
//   latency cover, never drains below 4 in steady state); ONE barrier per
//   tile placed AFTER the wait (cross-wave visibility of staged data).
//   Fragment ds_reads (12 b128/tile) interleaved into the burst gaps,
//   reusing dead registers (a0 after burst2, bb01 after burst3).
//   XOR swizzle (4 chunks): phys chunk = logical ^ (row&3), both sides;
//   read phases 2-way (free), gload writes linear. FP accumulation order
//   identical to BK=64 (same k-chunk sequence) -> bit-identical results.
//   NORM: fused per-head RMSNorm + RoPE epilogue for columns < 2048 (q,k).
// ---------------------------------------------------------------------------
template<typename CT, bool NORM>
__global__ __launch_bounds__(512) void gemm8ph(
        const short* __restrict__ A, const short* __restrict__ BT,
        const float* __restrict__ bias, CT* __restrict__ C,
        int M, int N, int K, int NX,
        const float* __restrict__ qw, const float* __restrict__ kw,
        const float* __restrict__ cos_t, const float* __restrict__ sin_t) {
    __shared__ short As[3][256 * 32];   // 48 KiB
    __shared__ short Bs[3][256 * 32];   // 48 KiB

    const int tid  = threadIdx.x;
    const int w    = tid >> 6;           // 0..7
    const int lane = tid & 63;
    const int l15  = lane & 15, lg = lane >> 4;   // lg in 0..3 = k-chunk
    const int wm = w >> 2, wn = w & 3;   // wave grid 2(M) x 4(N)

    const int nwg  = gridDim.x;
    const int cpx  = nwg >> 3;
    const int wgid = (blockIdx.x & 7) * cpx + (blockIdx.x >> 3);
    const int bx = wgid % NX, by = wgid / NX;
    const int m0 = by * 256, n0 = bx * 256;

    const int NT = K >> 5;               // K-tiles of 32

    // staging: instr j covers rows j*128 + w*16 + (lane>>2); 4 chunks of 8.
    const int sgrow = w * 16 + (lane >> 2);
    const int ksrc  = (((lane & 3) ^ ((lane >> 2) & 3)) * 8);

    auto stageA = [&](int t, int buf) {
        const size_t k0 = (size_t)t * 32;
#pragma unroll
        for (int j = 0; j < 2; ++j)
            gload16(A + (size_t)(m0 + j * 128 + sgrow) * K + k0 + ksrc,
                    &As[buf][(j * 128 + w * 16) * 32]);
    };
    auto stageB = [&](int t, int buf) {
        const size_t k0 = (size_t)t * 32;
#pragma unroll
        for (int j = 0; j < 2; ++j)
            gload16(BT + (size_t)(n0 + j * 128 + sgrow) * K + k0 + ksrc,
                    &Bs[buf][(j * 128 + w * 16) * 32]);
    };

    const int swz4 = l15 & 3;   // read-side chunk XOR (row&3 == l15&3)

    auto rdA = [&](int buf, int mh, s8v (&dst)[4]) {
#pragma unroll
        for (int i = 0; i < 4; ++i) {
            int row = wm * 128 + mh * 64 + i * 16 + l15;
            dst[i] = *(const s8v*)&As[buf][row * 32 + ((lg ^ swz4) * 8)];
        }
    };
    auto rdB2 = [&](int buf, int nh, s8v (&dst)[4]) {
#pragma unroll
        for (int ni = 0; ni < 2; ++ni) {
            int row = wn * 64 + (nh * 2 + ni) * 16 + l15;
            dst[nh * 2 + ni] = *(const s8v*)&Bs[buf][row * 32 + ((lg ^ swz4) * 8)];
        }
    };

    // prologue: stage tiles 0 and 1; confirm tile 0; read tile-0 fragments
    stageA(0, 0); stageB(0, 0);
    stageA(1, 1); stageB(1, 1);
    wait_vm4();
    bar();

    s8v a0[4], a1[4], bb[4];
    rdA(0, 0, a0);
    rdB2(0, 0, bb);
    rdB2(0, 1, bb);
    rdA(0, 1, a1);

    f32x4 acc[8][4] = {};

    for (int t = 0; t < NT; ++t) {
        const int b2 = (t + 2) % 3;      // stage target
        const int nb = (t + 1) % 3;      // next tile's buffer (reads)
        const bool more = (t + 1 < NT);

        if (t + 2 < NT) { stageA(t + 2, b2); stageB(t + 2, b2); }
        if (t + 2 < NT) wait_vm4(); else wait_vm0();   // t+1's stages landed
        bar();                                          // ...visible to all

        // burst1: mh0 x ni0/1
        __builtin_amdgcn_s_setprio(1);
#pragma unroll
        for (int i = 0; i < 4; ++i)
#pragma unroll
            for (int ni = 0; ni < 2; ++ni)
                acc[i][ni] = mfma_bf16(a0[i], bb[ni], acc[i][ni]);
        __builtin_amdgcn_s_setprio(0);

        // burst2: mh0 x ni2/3  (last use of a0)
        __builtin_amdgcn_s_setprio(1);
#pragma unroll
        for (int i = 0; i < 4; ++i)
#pragma unroll
            for (int ni = 2; ni < 4; ++ni)
                acc[i][ni] = mfma_bf16(a0[i], bb[ni], acc[i][ni]);
        __builtin_amdgcn_s_setprio(0);

        if (more) rdA(nb, 0, a0);        // refill a0 (dead)

        // burst3: mh1 x ni0/1  (last use of bb[0..1])
        __builtin_amdgcn_s_setprio(1);
#pragma unroll
        for (int i = 0; i < 4; ++i)
#pragma unroll
            for (int ni = 0; ni < 2; ++ni)
                acc[4 + i][ni] = mfma_bf16(a1[i], bb[ni], acc[4 + i][ni]);
        __builtin_amdgcn_s_setprio(0);

        if (more) rdB2(nb, 0, bb);       // refill bb01 (dead)

        // burst4: mh1 x ni2/3  (last use of a1, bb[2..3])
        __builtin_amdgcn_s_setprio(1);
#pragma unroll
        for (int i = 0; i < 4; ++i)
#pragma unroll
            for (int ni = 2; ni < 4; ++ni)
                acc[4 + i][ni] = mfma_bf16(a1[i], bb[ni], acc[4 + i][ni]);
        __builtin_amdgcn_s_setprio(0);

        if (more) { rdB2(nb, 1, bb); rdA(nb, 1, a1); }
    }

    // ---------------- epilogue ----------------
    const int colbase = n0 + wn * 64;
    if constexpr (NORM) {
        if (colbase < 2048) {
            const float* nw = (colbase < 1024) ? qw : kw;
            float wv[4], bv[4];
#pragma unroll
            for (int ni = 0; ni < 4; ++ni) {
                wv[ni] = nw[16 * ni + l15];
                bv[ni] = bias[colbase + 16 * ni + l15];
            }
#pragma unroll
            for (int mi = 0; mi < 8; ++mi) {
#pragma unroll
                for (int r = 0; r < 4; ++r) {
                    int row = m0 + wm * 128 + mi * 16 + lg * 4 + r;
                    int s = row & (S_ - 1);
                    float v[4];
#pragma unroll
                    for (int ni = 0; ni < 4; ++ni) v[ni] = acc[mi][ni][r] + bv[ni];
                    float ss = v[0]*v[0] + v[1]*v[1] + v[2]*v[2] + v[3]*v[3];
                    ss += __shfl_xor(ss, 1);
                    ss += __shfl_xor(ss, 2);
                    ss += __shfl_xor(ss, 4);
                    ss += __shfl_xor(ss, 8);
                    float rms = rsqrtf(ss * (1.0f / 64.0f) + 1e-6f);
                    float xn[4];
#pragma unroll
                    for (int ni = 0; ni < 4; ++ni) xn[ni] = v[ni] * rms * wv[ni];
#pragma unroll
                    for (int ni = 0; ni < 4; ++ni) {
                        int d = 16 * ni + l15;
                        float c  = cos_t[s * 64 + d];
                        float sn = sin_t[s * 64 + d];
                        float rot = (ni < 2) ? -xn[ni + 2] : xn[ni - 2];
                        C[(size_t)row * N + colbase + d] = (short)f2b(xn[ni] * c + rot * sn);
                    }
                }
            }
            return;
        }
    }
#pragma unroll
    for (int ni = 0; ni < 4; ++ni) {
        float bvv = bias[colbase + 16 * ni + l15];
#pragma unroll
        for (int mi = 0; mi < 8; ++mi) {
#pragma unroll
            for (int r = 0; r < 4; ++r) {
                size_t row = (size_t)(m0 + wm * 128 + mi * 16 + lg * 4 + r);
                int    col = colbase + 16 * ni + l15;
                float v = acc[mi][ni][r] + bvv;
                if constexpr (sizeof(CT) == 4) C[row * N + col] = v;
                else                           C[row * N + col] = (short)f2b(v);
            }
        }
    }
}

// ---------------------------------------------------------------------------
// MFMA flash attention, 32x32x16 dataflow — STATIC-MAX softmax (r19, as-is):
// P = exp2(st*SC - 12) (bound from RMSNorm+RoPE norms; shift-invariant).
// Same-head XCD band remap (FETCH 49 MB), full LDS swizzle (r17).
// ---------------------------------------------------------------------------
__global__ __launch_bounds__(256) void attn_mfma(const short* __restrict__ qkv,
                                                 short* __restrict__ attn) {
    __shared__ ushort_t pool[8192];            // Ks[64][64] | Vt[64][64], 16 KiB

    const float SC = 0.18033688011112042f;     // 0.125 * log2(e)
    const float M_ = 12.0f;                    // static max (exp2 units)

    const int tid  = threadIdx.x;
    const int w    = tid >> 6;
    const int lane = tid & 63;
    const int l31  = lane & 31, l5 = lane >> 5;

    const int bid = blockIdx.x;
    const int xcd = bid & 7;
    const int jj_ = bid >> 3;
    const int bh  = xcd * 32 + (jj_ >> 3);
    const int b   = bh >> 4, h = bh & 15;
    const int q0  = (jj_ & 7) * 128;

    const short* qbase = qkv + (size_t)b * S_ * TDIM + h * HD_;
    const short* kb_ = qbase + DIM_;
    const short* vb_ = qbase + 2 * DIM_;

    ushort_t* Ks = pool;
    ushort_t* Vt = pool + 4096;

    s8v qf[4];
#pragma unroll
    for (int kc = 0; kc < 4; ++kc)
        qf[kc] = *(const s8v*)(qbase + (size_t)(q0 + w * 32 + l31) * TDIM + kc * 16 + l5 * 8);

    f32x16 of0 = {}, of1 = {};
    float l_s = 0.f;

    const int kr   = tid >> 3;
    const int kch  = (((tid & 7) ^ (kr & 7)) << 3);
    const int va   = tid & 7;
    const int vkp  = tid >> 3;
    const int vp8  = va * 8;
    const int k2    = 2 * vkp;
    const int kperm = (k2 & 0x33) | ((k2 & 4) << 1) | ((k2 & 8) >> 1);
    const int rsw   = l31 & 7;
    const int vrx   = (l31 & 7) ^ (l31 >> 3);

    s8v kA, kB, vA, vB;
    auto prefetch = [&](int kt) {
        const short* kbt = kb_ + (size_t)kt * 64 * TDIM;
        const short* vbt = vb_ + (size_t)kt * 64 * TDIM;
        kA = *(const s8v*)(kbt + (size_t)kr * TDIM + (tid & 7) * 8);
        kB = *(const s8v*)(kbt + (size_t)(kr + 32) * TDIM + (tid & 7) * 8);
        vA = *(const s8v*)(vbt + (size_t)k2 * TDIM + vp8);
        vB = *(const s8v*)(vbt + (size_t)(k2 + 1) * TDIM + vp8);
    };
    prefetch(0);

    for (int kt = 0; kt < 16; ++kt) {
        *(s8v*)&Ks[kr * 64 + kch]        = kA;
        *(s8v*)&Ks[(kr + 32) * 64 + kch] = kB;
#pragma unroll
        for (int j = 0; j < 8; ++j) {
            uint_t pk = (ushort_t)vA[j] | ((uint_t)(ushort_t)vB[j] << 16);
            int pcol = ((((kperm >> 3) ^ j ^ va) << 3) | (kperm & 7));
            *(uint_t*)&Vt[(vp8 + j) * 64 + pcol] = pk;
        }
        __syncthreads();

        if (kt < 15) prefetch(kt + 1);

        f32x16 st0 = {}, st1 = {};
        __builtin_amdgcn_s_setprio(1);
#pragma unroll
        for (int kc = 0; kc < 4; ++kc) {
            int pc = (((2 * kc + l5) ^ rsw) << 3);
            s8v kf0 = *(const s8v*)&Ks[l31 * 64 + pc];
            s8v kf1 = *(const s8v*)&Ks[(32 + l31) * 64 + pc];
            st0 = mfma32_bf16(kf0, qf[kc], st0);
            st1 = mfma32_bf16(kf1, qf[kc], st1);
        }
        __builtin_amdgcn_s_setprio(0);

        float la = 0.f, lb = 0.f, lc = 0.f, ld = 0.f;
#pragma unroll
        for (int r = 0; r < 16; r += 2) {
            float p00 = exp2f(__builtin_fmaf(st0[r],     SC, -M_));
            float p01 = exp2f(__builtin_fmaf(st0[r + 1], SC, -M_));
            float p10 = exp2f(__builtin_fmaf(st1[r],     SC, -M_));
            float p11 = exp2f(__builtin_fmaf(st1[r + 1], SC, -M_));
            st0[r] = p00; st0[r + 1] = p01;
            st1[r] = p10; st1[r + 1] = p11;
            la += p00; lb += p01; lc += p10; ld += p11;
        }
        float ls = (la + lb) + (lc + ld);
        ls += __shfl_xor(ls, 32);
        l_s += ls;

        uint_t P20[8], P21[8];
#pragma unroll
        for (int i = 0; i < 8; ++i) {
            P20[i] = cvt_pk_bf16(st0[2 * i], st0[2 * i + 1]);
            P21[i] = cvt_pk_bf16(st1[2 * i], st1[2 * i + 1]);
        }

        __builtin_amdgcn_s_setprio(1);
#pragma unroll
        for (int kb = 0; kb < 2; ++kb) {
            const uint_t* P2 = kb ? P21 : P20;
#pragma unroll
            for (int c = 0; c < 2; ++c) {
                union { uint_t u[4]; s8v v; } pf;
                pf.u[0] = P2[4 * c + 0];
                pf.u[1] = P2[4 * c + 1];
                pf.u[2] = P2[4 * c + 2];
                pf.u[3] = P2[4 * c + 3];

                int pc0 = (((4 * kb + 2 * c + l5) ^ vrx) << 3);
                int pc1 = pc0 ^ 32;
                s8v vf0 = *(const s8v*)&Vt[l31 * 64 + pc0];
                s8v vf1 = *(const s8v*)&Vt[(32 + l31) * 64 + pc1];
                of0 = mfma32_bf16(vf0, pf.v, of0);
                of1 = mfma32_bf16(vf1, pf.v, of1);
            }
        }
        __builtin_amdgcn_s_setprio(0);
        __syncthreads();
    }

    float inv = 1.0f / l_s;
    ushort_t* OL = pool + w * 2048;
#pragma unroll
    for (int r = 0; r < 16; r += 2) {
        int d = (r & 3) + 8 * (r >> 2) + 4 * l5;
        uint_t p0 = cvt_pk_bf16(of0[r] * inv, of0[r + 1] * inv);
        uint_t p1 = cvt_pk_bf16(of1[r] * inv, of1[r + 1] * inv);
        int c0 = d, c1 = 32 + d;
        int pc0 = (((c0 >> 3) ^ (l31 & 7)) << 3) | (c0 & 7);
        int pc1 = (((c1 >> 3) ^ (l31 & 7)) << 3) | (c1 & 7);
        *(uint_t*)&OL[l31 * 64 + pc0] = p0;
        *(uint_t*)&OL[l31 * 64 + pc1] = p1;
    }
#pragma unroll
    for (int i = 0; i < 4; ++i) {
        int idx = lane + i * 64;
        int row = idx >> 3, ch = idx & 7;
        int pch = ((ch ^ (row & 7)) << 3);
        *(s8v*)&attn[((size_t)b * S_ + q0 + w * 32 + row) * DIM_ + h * HD_ + ch * 8] =
            *(const s8v*)&OL[row * 64 + pch];
    }
}

// ---------------------------------------------------------------------------
extern "C" void kernel_launch(void* const* d_in, const int* in_sizes, int n_in,
                              void* d_out, int out_size, void* d_ws, size_t ws_size,
                              hipStream_t stream) {
    const float* x        = (const float*)d_in[0];
    const float* w_qkv    = (const float*)d_in[1];
    const float* b_qkv    = (const float*)d_in[2];
    const float* q_norm_w = (const float*)d_in[3];
    const float* k_norm_w = (const float*)d_in[4];
    const float* w_out    = (const float*)d_in[5];
    const float* b_out    = (const float*)d_in[6];
    float* out = (float*)d_out;

    const size_t OFF_QKV = 0;                          //  96 MiB: qkv bf16
    const size_t OFF_ATT = 100663296;                  //  32 MiB: attn bf16
    const size_t OFF_XB  = OFF_ATT + 33554432;         //  32 MiB: x bf16
    const size_t OFF_WQ  = OFF_XB + 33554432;          //   6 MiB: w_qkv^T bf16
    const size_t OFF_WO  = OFF_WQ + 6291456;           //   2 MiB: w_out^T bf16
    const size_t OFF_CT  = OFF_WO + 2097152;           // 256 KiB: cos table
    const size_t OFF_ST  = OFF_CT + 262144;            // 256 KiB: sin table
    const size_t NEED    = OFF_ST + 262144;

    if (ws_size < NEED) {
        hipMemsetAsync(d_out, 0, (size_t)out_size * sizeof(float), stream);
        return;
    }

    char* ws = (char*)d_ws;
    short* qkv   = (short*)(ws + OFF_QKV);
    short* attnb = (short*)(ws + OFF_ATT);
    short* xb    = (short*)(ws + OFF_XB);
    short* wqkvT = (short*)(ws + OFF_WQ);
    short* woutT = (short*)(ws + OFF_WO);
    float* cos_t = (float*)(ws + OFF_CT);
    float* sin_t = (float*)(ws + OFF_ST);

    // 0: tables, conversions, weight transposes
    rope_tables<<<dim3(256), dim3(256), 0, stream>>>(cos_t, sin_t);
    f32_to_bf16_vec<<<dim3(8192), dim3(256), 0, stream>>>(x, xb, 2097152);
    transpose_to_bf16<<<dim3(96, 32), dim3(256), 0, stream>>>(w_qkv, wqkvT, 1024, 3072);
    transpose_to_bf16<<<dim3(32, 32), dim3(256), 0, stream>>>(w_out, woutT, 1024, 1024);

    // 1: qkv = x @ w_qkv + b_qkv, fused RMSNorm+RoPE epilogue on q,k columns.
    gemm8ph<short, true><<<dim3(768), dim3(512), 0, stream>>>(
        xb, wqkvT, b_qkv, qkv, 16384, 3072, 1024, 12,
        q_norm_w, k_norm_w, cos_t, sin_t);

    // 2: flash attention -> attnb (bf16)
    attn_mfma<<<dim3(2048), dim3(256), 0, stream>>>(qkv, attnb);

    // 3: out = attn @ w_out + b_out (fp32 out)
    gemm8ph<float, false><<<dim3(256), dim3(512), 0, stream>>>(
        attnb, woutT, b_out, out, 16384, 1024, 1024, 4,
        nullptr, nullptr, nullptr, nullptr);
}

// Round 21
// 277.082 us; speedup vs baseline: 1.0752x; 1.0752x over previous
//
#include <hip/hip_runtime.h>
#include <cstdint>
#include <cstddef>

#define B_    16
#define S_    1024
#define DIM_  1024
#define H_    16
#define HD_   64
#define TDIM  3072   // 3*DIM

typedef unsigned short ushort_t;
typedef unsigned int   uint_t;
typedef __attribute__((ext_vector_type(8)))  short s8v;    // 8 bf16 = 4 VGPRs
typedef __attribute__((ext_vector_type(4)))  float f32x4;
typedef __attribute__((ext_vector_type(16))) float f32x16;

__device__ __forceinline__ float b2f(ushort_t u) {
    union { uint_t i; float f; } t; t.i = (uint_t)u << 16; return t.f;
}
__device__ __forceinline__ ushort_t f2b(float f) {
    union { float f; uint_t i; } t; t.f = f;
    uint_t r = t.i + 0x7FFFu + ((t.i >> 16) & 1u);   // RNE
    return (ushort_t)(r >> 16);
}
__device__ __forceinline__ uint_t cvt_pk_bf16(float a, float b) {
    uint_t r;
    asm("v_cvt_pk_bf16_f32 %0, %1, %2" : "=v"(r) : "v"(a), "v"(b));
    return r;
}

// 16x16x32: D[m][n] += sum_k A[m,k]*B[k,n]
// D-frag (HW-verified m89/m91): col=lane&15, row=(lane>>4)*4+reg.
__device__ __forceinline__ f32x4 mfma_bf16(s8v a, s8v b, f32x4 c) {
    asm volatile("v_mfma_f32_16x16x32_bf16 %0, %1, %2, %0" : "+v"(c) : "v"(a), "v"(b));
    return c;
}
// 32x32x16: D-frag (HW-verified m74/m101): col=lane&31, row=(reg&3)+8*(reg>>2)+4*(lane>>5)
__device__ __forceinline__ f32x16 mfma32_bf16(s8v a, s8v b, f32x16 c) {
    asm volatile("v_mfma_f32_32x32x16_bf16 %0, %1, %2, %0" : "+v"(c) : "v"(a), "v"(b));
    return c;
}

// async global->LDS, 16B per lane; LDS dest = wave-uniform base + lane*16.
__device__ __forceinline__ void gload16(const void* g, void* l) {
    __builtin_amdgcn_global_load_lds(
        (const __attribute__((address_space(1))) uint_t*)g,
        (__attribute__((address_space(3))) uint_t*)l, 16, 0, 0);
}

// raw barrier (no compiler vmcnt drain) + explicit vm waits
__device__ __forceinline__ void bar() {
    asm volatile("" ::: "memory");
    __builtin_amdgcn_s_barrier();
    asm volatile("" ::: "memory");
}
__device__ __forceinline__ void wait_vm0() {
    asm volatile("s_waitcnt vmcnt(0)" ::: "memory");
}
__device__ __forceinline__ void wait_vm4() {
    asm volatile("s_waitcnt vmcnt(4)" ::: "memory");
}

// ---------------------------------------------------------------------------
// Fused prep kernel: block-range dispatch over 4 independent jobs
//   [0, 8192):       x fp32 -> bf16 (8 elem/thread)
//   [8192, 11264):   w_qkv [1024][3072] -> wqkvT [3072][1024] bf16
//   [11264, 12288):  w_out [1024][1024] -> woutT bf16
//   [12288, 12544):  RoPE cos/sin tables [S][HD]
// ---------------------------------------------------------------------------
__device__ __forceinline__ void transpose_job(const float* __restrict__ Wsrc,
                                              short* __restrict__ WT,
                                              int K, int N, int bx, int by,
                                              float (*t)[33]) {
    int tx = threadIdx.x & 31, ty = threadIdx.x >> 5;   // ty 0..7
    int n0 = bx * 32, k0 = by * 32;
#pragma unroll
    for (int i = 0; i < 4; ++i)
        t[ty + 8 * i][tx] = Wsrc[(size_t)(k0 + ty + 8 * i) * N + n0 + tx];
    __syncthreads();
#pragma unroll
    for (int i = 0; i < 4; ++i)
        WT[(size_t)(n0 + ty + 8 * i) * K + k0 + tx] = (short)f2b(t[tx][ty + 8 * i]);
}

__global__ __launch_bounds__(256) void prep_all(const float* __restrict__ x,
                                                short* __restrict__ xb,
                                                const float* __restrict__ w_qkv,
                                                short* __restrict__ wqkvT,
                                                const float* __restrict__ w_out,
                                                short* __restrict__ woutT,
                                                float* __restrict__ cos_t,
                                                float* __restrict__ sin_t) {
    __shared__ float t[32][33];
    const int bid = blockIdx.x;
    if (bid < 8192) {
        int i = bid * 256 + threadIdx.x;           // < 2097152
        float4 a = *(const float4*)(x + (size_t)i * 8);
        float4 b = *(const float4*)(x + (size_t)i * 8 + 4);
        s8v v;
        v[0] = (short)f2b(a.x); v[1] = (short)f2b(a.y);
        v[2] = (short)f2b(a.z); v[3] = (short)f2b(a.w);
        v[4] = (short)f2b(b.x); v[5] = (short)f2b(b.y);
        v[6] = (short)f2b(b.z); v[7] = (short)f2b(b.w);
        *(s8v*)(xb + (size_t)i * 8) = v;
    } else if (bid < 11264) {
        int idx = bid - 8192;                      // w_qkv: grid 96 x 32
        transpose_job(w_qkv, wqkvT, 1024, 3072, idx % 96, idx / 96, t);
    } else if (bid < 12288) {
        int idx = bid - 11264;                     // w_out: grid 32 x 32
        transpose_job(w_out, woutT, 1024, 1024, idx % 32, idx / 32, t);
    } else {
        int idx = (bid - 12288) * 256 + threadIdx.x;   // 0 .. 65535
        int s = idx >> 6;
        int d = idx & 63;
        int pos = (d < 32) ? (s >> 5) : (s & 31);
        int i   = (d & 31) >> 1;
        float freq  = expf(-(float)i * 0.5756462732485115f);   // ln(10000)/16
        float angle = (float)pos * 0.5f * freq;
        cos_t[idx] = cosf(angle);
        sin_t[idx] = sinf(angle);
    }
}

// ---------------------------------------------------------------------------
// 256x256 bf16 MFMA GEMM, BK=64, tile-ahead ds_read pipelining (round-13/19
// version, best-known: 123 us qkv, MfmaUtil 36%, zero bank conflicts).
//   A double-buffered, B triple-buffered (160 KiB LDS); counted vmcnt(4) at
//   the boundary; all 24 fragment ds_reads for tile t+1 issued at the end of
//   tile t (12 post-barrier overlapping burst4, 12 after). 8-chunk XOR
//   swizzle (col>>3)^(row&7), both sides.
//   NORM: fused per-head RMSNorm + RoPE epilogue for columns < 2048 (q,k).
// ---------------------------------------------------------------------------
template<typename CT, bool NORM>
__global__ __launch_bounds__(512) void gemm8ph(
        const short* __restrict__ A, const short* __restrict__ BT,
        const float* __restrict__ bias, CT* __restrict__ C,
        int M, int N, int K, int NX,
        const float* __restrict__ qw, const float* __restrict__ kw,
        const float* __restrict__ cos_t, const float* __restrict__ sin_t) {
    __shared__ short As[2][256 * 64];   // 64 KiB
    __shared__ short Bs[3][256 * 64];   // 96 KiB

    const int tid  = threadIdx.x;
    const int w    = tid >> 6;           // 0..7
    const int lane = tid & 63;
    const int l15  = lane & 15, lg = lane >> 4;
    const int wm = w >> 2, wn = w & 3;   // wave grid 2(M) x 4(N)

    const int nwg  = gridDim.x;
    const int cpx  = nwg >> 3;
    const int wgid = (blockIdx.x & 7) * cpx + (blockIdx.x >> 3);
    const int bx = wgid % NX, by = wgid / NX;
    const int m0 = by * 256, n0 = bx * 256;

    const int NT = K >> 6;               // K-tiles of 64

    const int sgrow = w * 8 + (lane >> 3);            // + j*64
    const int ksrc  = (((lane & 7) ^ (lane >> 3)) * 8);

    auto stageA = [&](int t, int buf) {
        const size_t k0 = (size_t)t * 64;
#pragma unroll
        for (int j = 0; j < 4; ++j)
            gload16(A + (size_t)(m0 + j * 64 + sgrow) * K + k0 + ksrc,
                    &As[buf][(j * 64 + w * 8) * 64]);
    };
    auto stageB = [&](int t, int buf) {
        const size_t k0 = (size_t)t * 64;
#pragma unroll
        for (int j = 0; j < 4; ++j)
            gload16(BT + (size_t)(n0 + j * 64 + sgrow) * K + k0 + ksrc,
                    &Bs[buf][(j * 64 + w * 8) * 64]);
    };

    const int swz = l15 & 7;

    auto rdA = [&](int buf, int mh, s8v (&dst)[4][2]) {
#pragma unroll
        for (int i = 0; i < 4; ++i) {
            int row = wm * 128 + mh * 64 + i * 16 + l15;
#pragma unroll
            for (int kk = 0; kk < 2; ++kk)
                dst[i][kk] = *(const s8v*)&As[buf][row * 64 + (((kk * 4 + lg) ^ swz) * 8)];
        }
    };
    auto rdB = [&](int buf, int nh, s8v (&dst)[4][2]) {
#pragma unroll
        for (int ni = 0; ni < 2; ++ni) {
            int row = wn * 64 + (nh * 2 + ni) * 16 + l15;
#pragma unroll
            for (int kk = 0; kk < 2; ++kk)
                dst[nh * 2 + ni][kk] = *(const s8v*)&Bs[buf][row * 64 + (((kk * 4 + lg) ^ swz) * 8)];
        }
    };

    stageA(0, 0);
    stageB(0, 0);
    stageB(1, 1);
    wait_vm4();
    bar();

    s8v a0[4][2], a1[4][2], bb[4][2];
    rdA(0, 0, a0);
    rdB(0, 0, bb);
    rdB(0, 1, bb);
    rdA(0, 1, a1);

    f32x4 acc[8][4] = {};

    int bufB = 0;
    for (int t = 0; t < NT; ++t) {
        const int bufA  = t & 1;
        const int nbufB = (bufB == 2) ? 0 : bufB + 1;   // (t+1)%3
        const int sbufB = (nbufB == 2) ? 0 : nbufB + 1; // (t+2)%3

        if (t + 1 < NT) stageA(t + 1, bufA ^ 1);
        if (t + 2 < NT) stageB(t + 2, sbufB);

        __builtin_amdgcn_s_setprio(1);
#pragma unroll
        for (int i = 0; i < 4; ++i)
#pragma unroll
            for (int ni = 0; ni < 2; ++ni)
#pragma unroll
                for (int kk = 0; kk < 2; ++kk)
                    acc[i][ni] = mfma_bf16(a0[i][kk], bb[ni][kk], acc[i][ni]);
        __builtin_amdgcn_s_setprio(0);

        __builtin_amdgcn_s_setprio(1);
#pragma unroll
        for (int i = 0; i < 4; ++i)
#pragma unroll
            for (int ni = 2; ni < 4; ++ni)
#pragma unroll
                for (int kk = 0; kk < 2; ++kk)
                    acc[i][ni] = mfma_bf16(a0[i][kk], bb[ni][kk], acc[i][ni]);
        __builtin_amdgcn_s_setprio(0);

        __builtin_amdgcn_s_setprio(1);
#pragma unroll
        for (int i = 0; i < 4; ++i)
#pragma unroll
            for (int ni = 0; ni < 2; ++ni)
#pragma unroll
                for (int kk = 0; kk < 2; ++kk)
                    acc[4 + i][ni] = mfma_bf16(a1[i][kk], bb[ni][kk], acc[4 + i][ni]);
        __builtin_amdgcn_s_setprio(0);

        if (t < NT - 2) wait_vm4(); else wait_vm0();
        bar();

        if (t + 1 < NT) {
            rdA(bufA ^ 1, 0, a0);
            rdB(nbufB, 0, bb);
        }

        __builtin_amdgcn_s_setprio(1);
#pragma unroll
        for (int i = 0; i < 4; ++i)
#pragma unroll
            for (int ni = 2; ni < 4; ++ni)
#pragma unroll
                for (int kk = 0; kk < 2; ++kk)
                    acc[4 + i][ni] = mfma_bf16(a1[i][kk], bb[ni][kk], acc[4 + i][ni]);
        __builtin_amdgcn_s_setprio(0);

        if (t + 1 < NT) {
            rdB(nbufB, 1, bb);
            rdA(bufA ^ 1, 1, a1);
        }
        bufB = nbufB;
    }

    // ---------------- epilogue ----------------
    const int colbase = n0 + wn * 64;
    if constexpr (NORM) {
        if (colbase < 2048) {
            const float* nw = (colbase < 1024) ? qw : kw;
            float wv[4], bv[4];
#pragma unroll
            for (int ni = 0; ni < 4; ++ni) {
                wv[ni] = nw[16 * ni + l15];
                bv[ni] = bias[colbase + 16 * ni + l15];
            }
#pragma unroll
            for (int mi = 0; mi < 8; ++mi) {
#pragma unroll
                for (int r = 0; r < 4; ++r) {
                    int row = m0 + wm * 128 + mi * 16 + lg * 4 + r;
                    int s = row & (S_ - 1);
                    float v[4];
#pragma unroll
                    for (int ni = 0; ni < 4; ++ni) v[ni] = acc[mi][ni][r] + bv[ni];
                    float ss = v[0]*v[0] + v[1]*v[1] + v[2]*v[2] + v[3]*v[3];
                    ss += __shfl_xor(ss, 1);
                    ss += __shfl_xor(ss, 2);
                    ss += __shfl_xor(ss, 4);
                    ss += __shfl_xor(ss, 8);
                    float rms = rsqrtf(ss * (1.0f / 64.0f) + 1e-6f);
                    float xn[4];
#pragma unroll
                    for (int ni = 0; ni < 4; ++ni) xn[ni] = v[ni] * rms * wv[ni];
#pragma unroll
                    for (int ni = 0; ni < 4; ++ni) {
                        int d = 16 * ni + l15;
                        float c  = cos_t[s * 64 + d];
                        float sn = sin_t[s * 64 + d];
                        float rot = (ni < 2) ? -xn[ni + 2] : xn[ni - 2];
                        C[(size_t)row * N + colbase + d] = (short)f2b(xn[ni] * c + rot * sn);
                    }
                }
            }
            return;
        }
    }
#pragma unroll
    for (int ni = 0; ni < 4; ++ni) {
        float bvv = bias[colbase + 16 * ni + l15];
#pragma unroll
        for (int mi = 0; mi < 8; ++mi) {
#pragma unroll
            for (int r = 0; r < 4; ++r) {
                size_t row = (size_t)(m0 + wm * 128 + mi * 16 + lg * 4 + r);
                int    col = colbase + 16 * ni + l15;
                float v = acc[mi][ni][r] + bvv;
                if constexpr (sizeof(CT) == 4) C[row * N + col] = v;
                else                           C[row * N + col] = (short)f2b(v);
            }
        }
    }
}

// ---------------------------------------------------------------------------
// MFMA flash attention, 32x32x16 dataflow — STATIC-MAX softmax (r19, as-is):
// P = exp2(st*SC - 12) (bound from RMSNorm+RoPE norms; shift-invariant).
// Same-head XCD band remap (FETCH 49 MB), full LDS swizzle (r17).
// ---------------------------------------------------------------------------
__global__ __launch_bounds__(256) void attn_mfma(const short* __restrict__ qkv,
                                                 short* __restrict__ attn) {
    __shared__ ushort_t pool[8192];            // Ks[64][64] | Vt[64][64], 16 KiB

    const float SC = 0.18033688011112042f;     // 0.125 * log2(e)
    const float M_ = 12.0f;                    // static max (exp2 units)

    const int tid  = threadIdx.x;
    const int w    = tid >> 6;
    const int lane = tid & 63;
    const int l31  = lane & 31, l5 = lane >> 5;

    const int bid = blockIdx.x;
    const int xcd = bid & 7;
    const int jj_ = bid >> 3;
    const int bh  = xcd * 32 + (jj_ >> 3);
    const int b   = bh >> 4, h = bh & 15;
    const int q0  = (jj_ & 7) * 128;

    const short* qbase = qkv + (size_t)b * S_ * TDIM + h * HD_;
    const short* kb_ = qbase + DIM_;
    const short* vb_ = qbase + 2 * DIM_;

    ushort_t* Ks = pool;
    ushort_t* Vt = pool + 4096;

    s8v qf[4];
#pragma unroll
    for (int kc = 0; kc < 4; ++kc)
        qf[kc] = *(const s8v*)(qbase + (size_t)(q0 + w * 32 + l31) * TDIM + kc * 16 + l5 * 8);

    f32x16 of0 = {}, of1 = {};
    float l_s = 0.f;

    const int kr   = tid >> 3;
    const int kch  = (((tid & 7) ^ (kr & 7)) << 3);
    const int va   = tid & 7;
    const int vkp  = tid >> 3;
    const int vp8  = va * 8;
    const int k2    = 2 * vkp;
    const int kperm = (k2 & 0x33) | ((k2 & 4) << 1) | ((k2 & 8) >> 1);
    const int rsw   = l31 & 7;
    const int vrx   = (l31 & 7) ^ (l31 >> 3);

    s8v kA, kB, vA, vB;
    auto prefetch = [&](int kt) {
        const short* kbt = kb_ + (size_t)kt * 64 * TDIM;
        const short* vbt = vb_ + (size_t)kt * 64 * TDIM;
        kA = *(const s8v*)(kbt + (size_t)kr * TDIM + (tid & 7) * 8);
        kB = *(const s8v*)(kbt + (size_t)(kr + 32) * TDIM + (tid & 7) * 8);
        vA = *(const s8v*)(vbt + (size_t)k2 * TDIM + vp8);
        vB = *(const s8v*)(vbt + (size_t)(k2 + 1) * TDIM + vp8);
    };
    prefetch(0);

    for (int kt = 0; kt < 16; ++kt) {
        *(s8v*)&Ks[kr * 64 + kch]        = kA;
        *(s8v*)&Ks[(kr + 32) * 64 + kch] = kB;
#pragma unroll
        for (int j = 0; j < 8; ++j) {
            uint_t pk = (ushort_t)vA[j] | ((uint_t)(ushort_t)vB[j] << 16);
            int pcol = ((((kperm >> 3) ^ j ^ va) << 3) | (kperm & 7));
            *(uint_t*)&Vt[(vp8 + j) * 64 + pcol] = pk;
        }
        __syncthreads();

        if (kt < 15) prefetch(kt + 1);

        f32x16 st0 = {}, st1 = {};
        __builtin_amdgcn_s_setprio(1);
#pragma unroll
        for (int kc = 0; kc < 4; ++kc) {
            int pc = (((2 * kc + l5) ^ rsw) << 3);
            s8v kf0 = *(const s8v*)&Ks[l31 * 64 + pc];
            s8v kf1 = *(const s8v*)&Ks[(32 + l31) * 64 + pc];
            st0 = mfma32_bf16(kf0, qf[kc], st0);
            st1 = mfma32_bf16(kf1, qf[kc], st1);
        }
        __builtin_amdgcn_s_setprio(0);

        float la = 0.f, lb = 0.f, lc = 0.f, ld = 0.f;
#pragma unroll
        for (int r = 0; r < 16; r += 2) {
            float p00 = exp2f(__builtin_fmaf(st0[r],     SC, -M_));
            float p01 = exp2f(__builtin_fmaf(st0[r + 1], SC, -M_));
            float p10 = exp2f(__builtin_fmaf(st1[r],     SC, -M_));
            float p11 = exp2f(__builtin_fmaf(st1[r + 1], SC, -M_));
            st0[r] = p00; st0[r + 1] = p01;
            st1[r] = p10; st1[r + 1] = p11;
            la += p00; lb += p01; lc += p10; ld += p11;
        }
        float ls = (la + lb) + (lc + ld);
        ls += __shfl_xor(ls, 32);
        l_s += ls;

        uint_t P20[8], P21[8];
#pragma unroll
        for (int i = 0; i < 8; ++i) {
            P20[i] = cvt_pk_bf16(st0[2 * i], st0[2 * i + 1]);
            P21[i] = cvt_pk_bf16(st1[2 * i], st1[2 * i + 1]);
        }

        __builtin_amdgcn_s_setprio(1);
#pragma unroll
        for (int kb = 0; kb < 2; ++kb) {
            const uint_t* P2 = kb ? P21 : P20;
#pragma unroll
            for (int c = 0; c < 2; ++c) {
                union { uint_t u[4]; s8v v; } pf;
                pf.u[0] = P2[4 * c + 0];
                pf.u[1] = P2[4 * c + 1];
                pf.u[2] = P2[4 * c + 2];
                pf.u[3] = P2[4 * c + 3];

                int pc0 = (((4 * kb + 2 * c + l5) ^ vrx) << 3);
                int pc1 = pc0 ^ 32;
                s8v vf0 = *(const s8v*)&Vt[l31 * 64 + pc0];
                s8v vf1 = *(const s8v*)&Vt[(32 + l31) * 64 + pc1];
                of0 = mfma32_bf16(vf0, pf.v, of0);
                of1 = mfma32_bf16(vf1, pf.v, of1);
            }
        }
        __builtin_amdgcn_s_setprio(0);
        __syncthreads();
    }

    float inv = 1.0f / l_s;
    ushort_t* OL = pool + w * 2048;
#pragma unroll
    for (int r = 0; r < 16; r += 2) {
        int d = (r & 3) + 8 * (r >> 2) + 4 * l5;
        uint_t p0 = cvt_pk_bf16(of0[r] * inv, of0[r + 1] * inv);
        uint_t p1 = cvt_pk_bf16(of1[r] * inv, of1[r + 1] * inv);
        int c0 = d, c1 = 32 + d;
        int pc0 = (((c0 >> 3) ^ (l31 & 7)) << 3) | (c0 & 7);
        int pc1 = (((c1 >> 3) ^ (l31 & 7)) << 3) | (c1 & 7);
        *(uint_t*)&OL[l31 * 64 + pc0] = p0;
        *(uint_t*)&OL[l31 * 64 + pc1] = p1;
    }
#pragma unroll
    for (int i = 0; i < 4; ++i) {
        int idx = lane + i * 64;
        int row = idx >> 3, ch = idx & 7;
        int pch = ((ch ^ (row & 7)) << 3);
        *(s8v*)&attn[((size_t)b * S_ + q0 + w * 32 + row) * DIM_ + h * HD_ + ch * 8] =
            *(const s8v*)&OL[row * 64 + pch];
    }
}

// ---------------------------------------------------------------------------
extern "C" void kernel_launch(void* const* d_in, const int* in_sizes, int n_in,
                              void* d_out, int out_size, void* d_ws, size_t ws_size,
                              hipStream_t stream) {
    const float* x        = (const float*)d_in[0];
    const float* w_qkv    = (const float*)d_in[1];
    const float* b_qkv    = (const float*)d_in[2];
    const float* q_norm_w = (const float*)d_in[3];
    const float* k_norm_w = (const float*)d_in[4];
    const float* w_out    = (const float*)d_in[5];
    const float* b_out    = (const float*)d_in[6];
    float* out = (float*)d_out;

    const size_t OFF_QKV = 0;                          //  96 MiB: qkv bf16
    const size_t OFF_ATT = 100663296;                  //  32 MiB: attn bf16
    const size_t OFF_XB  = OFF_ATT + 33554432;         //  32 MiB: x bf16
    const size_t OFF_WQ  = OFF_XB + 33554432;          //   6 MiB: w_qkv^T bf16
    const size_t OFF_WO  = OFF_WQ + 6291456;           //   2 MiB: w_out^T bf16
    const size_t OFF_CT  = OFF_WO + 2097152;           // 256 KiB: cos table
    const size_t OFF_ST  = OFF_CT + 262144;            // 256 KiB: sin table
    const size_t NEED    = OFF_ST + 262144;

    if (ws_size < NEED) {
        hipMemsetAsync(d_out, 0, (size_t)out_size * sizeof(float), stream);
        return;
    }

    char* ws = (char*)d_ws;
    short* qkv   = (short*)(ws + OFF_QKV);
    short* attnb = (short*)(ws + OFF_ATT);
    short* xb    = (short*)(ws + OFF_XB);
    short* wqkvT = (short*)(ws + OFF_WQ);
    short* woutT = (short*)(ws + OFF_WO);
    float* cos_t = (float*)(ws + OFF_CT);
    float* sin_t = (float*)(ws + OFF_ST);

    // 0: fused prep (x->bf16, both weight transposes, RoPE tables)
    prep_all<<<dim3(12544), dim3(256), 0, stream>>>(
        x, xb, w_qkv, wqkvT, w_out, woutT, cos_t, sin_t);

    // 1: qkv = x @ w_qkv + b_qkv, fused RMSNorm+RoPE epilogue on q,k columns.
    gemm8ph<short, true><<<dim3(768), dim3(512), 0, stream>>>(
        xb, wqkvT, b_qkv, qkv, 16384, 3072, 1024, 12,
        q_norm_w, k_norm_w, cos_t, sin_t);

    // 2: flash attention -> attnb (bf16)
    attn_mfma<<<dim3(2048), dim3(256), 0, stream>>>(qkv, attnb);

    // 3: out = attn @ w_out + b_out (fp32 out)
    gemm8ph<float, false><<<dim3(256), dim3(512), 0, stream>>>(
        attnb, woutT, b_out, out, 16384, 1024, 1024, 4,
        nullptr, nullptr, nullptr, nullptr);
}